// Round 1
// baseline (84.787 us; speedup 1.0000x reference)
//
#include <hip/hip_runtime.h>

#define BATCH 128
#define DIM 256
#define NTH 6
#define NF 1536          // NUM_FACTS
#define NODES 1023
#define NPAD 1024
#define OD 8
#define INV_TAU (1.0f/0.7f)
#define CLIP_EPS 1e-6f

// K2 tiling
#define BN2 32           // nodes per workgroup
#define KC2 96           // k-chunk per workgroup
#define KSPLIT 16        // 16 * 96 = 1536
#define GPITCH 104       // LDS row pitch (104%32==8 -> 2-way bank alias = free; 416B row, 16B aligned)

// ws layout (bytes)
#define OFF_FT   0            // fT [NF][BATCH] f32 = 786432
#define OFF_NUM  786432       // num [BATCH][NPAD] f32 = 524288
#define OFF_C    1310720      // csum [NPAD] f32 = 4096
#define OFF_S    1314816      // ssum [NPAD] f32 = 4096

__global__ __launch_bounds__(256) void k_facts(const float* __restrict__ x,
                                               const float* __restrict__ th,
                                               const float* __restrict__ sl,
                                               float* __restrict__ fT) {
    int idx = blockIdx.x * 256 + threadIdx.x;   // idx = k*128 + b
    int b = idx & 127;
    int k = idx >> 7;
    int d = k / NTH;
    float z = (x[b * DIM + d] - th[k]) * sl[k];
    fT[idx] = 1.0f / (1.0f + __expf(-z));
}

__global__ __launch_bounds__(256) void k_nodegemm(const float* __restrict__ logits,
                                                  const float* __restrict__ fT,
                                                  float* __restrict__ num,
                                                  float* __restrict__ csum,
                                                  float* __restrict__ ssum) {
    __shared__ float gs[BN2 * GPITCH];
    const int tid = threadIdx.x;
    const int tile = blockIdx.x >> 4;       // 0..31
    const int chunk = blockIdx.x & 15;      // 0..15
    const int n0 = tile * BN2;
    const int k0 = chunk * KC2;

    // ---- stage g = e1 - e2 into LDS; accumulate c (sum e2) and S (sum e1+e2)
    const int r = tid >> 3;                 // 0..31 node row
    const int l = tid & 7;                  // 0..7 lane in row
    const int n = n0 + r;
    float cpart = 0.f, spart = 0.f;
    if (n < NODES) {
        const float* row = logits + (size_t)n * (2 * NF) + k0;
        #pragma unroll
        for (int i = 0; i < KC2 / 8; ++i) {
            int k = l + i * 8;
            float e1 = __expf(row[k] * INV_TAU);
            float e2 = __expf(row[k + NF] * INV_TAU);
            gs[r * GPITCH + k] = e1 - e2;
            cpart += e2;
            spart += e1 + e2;
        }
    } else {
        #pragma unroll
        for (int i = 0; i < KC2 / 8; ++i) gs[r * GPITCH + l + i * 8] = 0.f;
    }
    // reduce c,S across the 8 lanes of this row
    cpart += __shfl_xor(cpart, 1); cpart += __shfl_xor(cpart, 2); cpart += __shfl_xor(cpart, 4);
    spart += __shfl_xor(spart, 1); spart += __shfl_xor(spart, 2); spart += __shfl_xor(spart, 4);
    if (l == 0 && n < NODES) {
        atomicAdd(&csum[n], cpart);
        atomicAdd(&ssum[n], spart);
    }
    __syncthreads();

    // ---- register-tiled GEMM: acc[b 4][n 4] over this k-chunk
    const int bq = tid & 31;                // 0..31 -> b0 = 4*bq
    const int nq = tid >> 5;                // 0..7  -> node sub-rows nq*4..+3
    const int b0 = bq * 4;
    float acc[4][4] = {};
    const float* fTp = fT + (size_t)k0 * BATCH + b0;

    #pragma unroll 6
    for (int kk = 0; kk < KC2; kk += 4) {
        float4 f0 = *(const float4*)(fTp + (kk + 0) * BATCH);
        float4 f1 = *(const float4*)(fTp + (kk + 1) * BATCH);
        float4 f2 = *(const float4*)(fTp + (kk + 2) * BATCH);
        float4 f3 = *(const float4*)(fTp + (kk + 3) * BATCH);
        #define STEP(j) { \
            float4 gv = *(const float4*)&gs[(nq * 4 + (j)) * GPITCH + kk]; \
            acc[0][j] += f0.x * gv.x + f1.x * gv.y + f2.x * gv.z + f3.x * gv.w; \
            acc[1][j] += f0.y * gv.x + f1.y * gv.y + f2.y * gv.z + f3.y * gv.w; \
            acc[2][j] += f0.z * gv.x + f1.z * gv.y + f2.z * gv.z + f3.z * gv.w; \
            acc[3][j] += f0.w * gv.x + f1.w * gv.y + f2.w * gv.z + f3.w * gv.w; }
        STEP(0) STEP(1) STEP(2) STEP(3)
        #undef STEP
    }

    #pragma unroll
    for (int j = 0; j < 4; ++j) {
        int nn = n0 + nq * 4 + j;
        if (nn < NODES) {
            #pragma unroll
            for (int i = 0; i < 4; ++i)
                atomicAdd(&num[(size_t)(b0 + i) * NPAD + nn], acc[i][j]);
        }
    }
}

__global__ __launch_bounds__(256) void k_tree(const float* __restrict__ num,
                                              const float* __restrict__ csum,
                                              const float* __restrict__ ssum,
                                              const float* __restrict__ LV,
                                              float* __restrict__ out) {
    __shared__ float tl[NODES];
    __shared__ float Abuf[512 * OD];
    __shared__ float Bbuf[256 * OD];
    const int b = blockIdx.x;
    const int tid = threadIdx.x;

    for (int n = tid; n < NODES; n += 256) {
        float tv = (num[(size_t)b * NPAD + n] + csum[n]) / ssum[n];
        tl[n] = fminf(fmaxf(tv, CLIP_EPS), 1.0f - CLIP_EPS);
    }
    __syncthreads();

    // depth-9 internal nodes (511..1022): combine leaf_value children
    for (int w = tid; w < 512 * OD; w += 256) {
        int i = w >> 3, o = w & 7;
        float tv = tl[511 + i];
        Abuf[w] = (1.0f - tv) * LV[i * 16 + o] + tv * LV[i * 16 + 8 + o];
    }
    __syncthreads();

    float* cur = Abuf;
    float* nxt = Bbuf;
    for (int lev = 8; lev >= 0; --lev) {
        int cnt = 1 << lev;
        int base = cnt - 1;
        for (int w = tid; w < cnt * OD; w += 256) {
            int i = w >> 3, o = w & 7;
            float tv = tl[base + i];
            nxt[w] = (1.0f - tv) * cur[i * 16 + o] + tv * cur[i * 16 + 8 + o];
        }
        __syncthreads();
        float* tmp = cur; cur = nxt; nxt = tmp;
    }
    if (tid < OD) out[b * OD + tid] = cur[tid];
}

extern "C" void kernel_launch(void* const* d_in, const int* in_sizes, int n_in,
                              void* d_out, int out_size, void* d_ws, size_t ws_size,
                              hipStream_t stream) {
    const float* x      = (const float*)d_in[0];
    const float* th     = (const float*)d_in[1];
    const float* sl     = (const float*)d_in[2];
    const float* logits = (const float*)d_in[3];
    const float* LV     = (const float*)d_in[4];
    // d_in[5] leaf_used, d_in[6] leaf_dir: encoded structurally in k_tree
    float* out = (float*)d_out;
    char* ws = (char*)d_ws;
    float* fT   = (float*)(ws + OFF_FT);
    float* num  = (float*)(ws + OFF_NUM);
    float* csum = (float*)(ws + OFF_C);
    float* ssum = (float*)(ws + OFF_S);

    // zero the atomic accumulators (num, csum, ssum are contiguous)
    hipMemsetAsync(num, 0, 524288 + 4096 + 4096, stream);

    k_facts<<<(NF * BATCH) / 256, 256, 0, stream>>>(x, th, sl, fT);
    k_nodegemm<<<32 * KSPLIT, 256, 0, stream>>>(logits, fT, num, csum, ssum);
    k_tree<<<BATCH, 256, 0, stream>>>(num, csum, ssum, LV, out);
}

// Round 2
// 33.514 us; speedup vs baseline: 2.5299x; 2.5299x over previous
//
#include <hip/hip_runtime.h>

#define BATCH 128
#define DIM 256
#define NTH 6
#define NF 1536          // NUM_FACTS
#define NODES 1023
#define NPAD 1024
#define OD 8
#define INV_TAU (1.0f/0.7f)
#define CLIP_EPS 1e-6f

// K2 tiling
#define BN2 32           // nodes per workgroup
#define KC2 96           // k-chunk per workgroup
#define KSPLIT 16        // 16 * 96 = 1536
#define GPITCH 104       // LDS row pitch (104%32==8 -> 2-way bank alias = free)

// ws layout (bytes)
#define OFF_FT   0            // fT [NF][BATCH] f32 = 786432
#define OFF_PART 786432       // partial [KSPLIT][BATCH][NPAD] f32 = 8388608
#define OFF_C    9175040      // csum [NPAD] f32 = 4096
#define OFF_S    9179136      // ssum [NPAD] f32 = 4096

__global__ __launch_bounds__(256) void k_facts(const float* __restrict__ x,
                                               const float* __restrict__ th,
                                               const float* __restrict__ sl,
                                               float* __restrict__ fT) {
    int idx = blockIdx.x * 256 + threadIdx.x;   // idx = k*128 + b
    int b = idx & 127;
    int k = idx >> 7;
    int d = k / NTH;
    float z = (x[b * DIM + d] - th[k]) * sl[k];
    fT[idx] = 1.0f / (1.0f + __expf(-z));
}

__global__ __launch_bounds__(256) void k_nodegemm(const float* __restrict__ logits,
                                                  const float* __restrict__ fT,
                                                  float* __restrict__ partial,
                                                  float* __restrict__ csum,
                                                  float* __restrict__ ssum) {
    __shared__ float gs[BN2 * GPITCH];
    const int tid = threadIdx.x;
    const int tile = blockIdx.x >> 4;       // 0..31
    const int chunk = blockIdx.x & 15;      // 0..15
    const int n0 = tile * BN2;
    const int k0 = chunk * KC2;

    // ---- stage g = e1 - e2 into LDS; accumulate c (sum e2) and S (sum e1+e2)
    const int r = tid >> 3;                 // 0..31 node row
    const int l = tid & 7;                  // 0..7 lane in row
    const int n = n0 + r;
    float cpart = 0.f, spart = 0.f;
    if (n < NODES) {
        const float* row = logits + (size_t)n * (2 * NF) + k0;
        #pragma unroll
        for (int i = 0; i < KC2 / 8; ++i) {
            int k = l + i * 8;
            float e1 = __expf(row[k] * INV_TAU);
            float e2 = __expf(row[k + NF] * INV_TAU);
            gs[r * GPITCH + k] = e1 - e2;
            cpart += e2;
            spart += e1 + e2;
        }
    } else {
        #pragma unroll
        for (int i = 0; i < KC2 / 8; ++i) gs[r * GPITCH + l + i * 8] = 0.f;
    }
    // reduce c,S across the 8 lanes of this row
    cpart += __shfl_xor(cpart, 1); cpart += __shfl_xor(cpart, 2); cpart += __shfl_xor(cpart, 4);
    spart += __shfl_xor(spart, 1); spart += __shfl_xor(spart, 2); spart += __shfl_xor(spart, 4);
    if (l == 0 && n < NODES) {
        atomicAdd(&csum[n], cpart);
        atomicAdd(&ssum[n], spart);
    }
    __syncthreads();

    // ---- register-tiled GEMM: acc[b 4][n 4] over this k-chunk
    const int bq = tid & 31;                // 0..31 -> b0 = 4*bq
    const int nq = tid >> 5;                // 0..7  -> node sub-rows nq*4..+3
    const int b0 = bq * 4;
    float acc[4][4] = {};
    const float* fTp = fT + (size_t)k0 * BATCH + b0;

    #pragma unroll 6
    for (int kk = 0; kk < KC2; kk += 4) {
        float4 f0 = *(const float4*)(fTp + (kk + 0) * BATCH);
        float4 f1 = *(const float4*)(fTp + (kk + 1) * BATCH);
        float4 f2 = *(const float4*)(fTp + (kk + 2) * BATCH);
        float4 f3 = *(const float4*)(fTp + (kk + 3) * BATCH);
        #define STEP(j) { \
            float4 gv = *(const float4*)&gs[(nq * 4 + (j)) * GPITCH + kk]; \
            acc[0][j] += f0.x * gv.x + f1.x * gv.y + f2.x * gv.z + f3.x * gv.w; \
            acc[1][j] += f0.y * gv.x + f1.y * gv.y + f2.y * gv.z + f3.y * gv.w; \
            acc[2][j] += f0.z * gv.x + f1.z * gv.y + f2.z * gv.z + f3.z * gv.w; \
            acc[3][j] += f0.w * gv.x + f1.w * gv.y + f2.w * gv.z + f3.w * gv.w; }
        STEP(0) STEP(1) STEP(2) STEP(3)
        #undef STEP
    }

    // ---- store partial tile (no atomics): partial[chunk][b][n]
    float* pdst = partial + (size_t)chunk * (BATCH * NPAD) + n0 + nq * 4;
    #pragma unroll
    for (int i = 0; i < 4; ++i) {
        float4 st = make_float4(acc[i][0], acc[i][1], acc[i][2], acc[i][3]);
        *(float4*)(pdst + (size_t)(b0 + i) * NPAD) = st;
    }
}

__global__ __launch_bounds__(256) void k_tree(const float* __restrict__ partial,
                                              const float* __restrict__ csum,
                                              const float* __restrict__ ssum,
                                              const float* __restrict__ LV,
                                              float* __restrict__ out) {
    __shared__ float tl[NODES];
    __shared__ float Abuf[512 * OD];
    __shared__ float Bbuf[256 * OD];
    const int b = blockIdx.x;
    const int tid = threadIdx.x;

    for (int n = tid; n < NODES; n += 256) {
        float s = 0.f;
        #pragma unroll
        for (int c = 0; c < KSPLIT; ++c)
            s += partial[(size_t)c * (BATCH * NPAD) + (size_t)b * NPAD + n];
        float tv = (s + csum[n]) / ssum[n];
        tl[n] = fminf(fmaxf(tv, CLIP_EPS), 1.0f - CLIP_EPS);
    }
    __syncthreads();

    // depth-9 internal nodes (511..1022): combine leaf_value children
    for (int w = tid; w < 512 * OD; w += 256) {
        int i = w >> 3, o = w & 7;
        float tv = tl[511 + i];
        Abuf[w] = (1.0f - tv) * LV[i * 16 + o] + tv * LV[i * 16 + 8 + o];
    }
    __syncthreads();

    float* cur = Abuf;
    float* nxt = Bbuf;
    for (int lev = 8; lev >= 0; --lev) {
        int cnt = 1 << lev;
        int base = cnt - 1;
        for (int w = tid; w < cnt * OD; w += 256) {
            int i = w >> 3, o = w & 7;
            float tv = tl[base + i];
            nxt[w] = (1.0f - tv) * cur[i * 16 + o] + tv * cur[i * 16 + 8 + o];
        }
        __syncthreads();
        float* tmp = cur; cur = nxt; nxt = tmp;
    }
    if (tid < OD) out[b * OD + tid] = cur[tid];
}

extern "C" void kernel_launch(void* const* d_in, const int* in_sizes, int n_in,
                              void* d_out, int out_size, void* d_ws, size_t ws_size,
                              hipStream_t stream) {
    const float* x      = (const float*)d_in[0];
    const float* th     = (const float*)d_in[1];
    const float* sl     = (const float*)d_in[2];
    const float* logits = (const float*)d_in[3];
    const float* LV     = (const float*)d_in[4];
    float* out = (float*)d_out;
    char* ws = (char*)d_ws;
    float* fT      = (float*)(ws + OFF_FT);
    float* partial = (float*)(ws + OFF_PART);
    float* csum    = (float*)(ws + OFF_C);
    float* ssum    = (float*)(ws + OFF_S);

    // zero only the small atomic accumulators (csum, ssum contiguous)
    hipMemsetAsync(csum, 0, 8192, stream);

    k_facts<<<(NF * BATCH) / 256, 256, 0, stream>>>(x, th, sl, fT);
    k_nodegemm<<<32 * KSPLIT, 256, 0, stream>>>(logits, fT, partial, csum, ssum);
    k_tree<<<BATCH, 256, 0, stream>>>(partial, csum, ssum, LV, out);
}